// Round 8
// baseline (517.530 us; speedup 1.0000x reference)
//
#include <hip/hip_runtime.h>

// TransformerBlock on MI355X (gfx950). fp32 I/O, bf16 MFMA compute.
// B=2 S=2048 D=1024 H=16 Dh=64 HIDDEN=4096, causal, exact GELU.
//
// Round 8 == Round 6 resubmit, attempt 3 (two broker-level failures, no
// bench data; source audited clean — see journal).
// Round 6: GEMM BK=64 / BN=64 (attention/LN/transposes unchanged from R5).
//   R5 post-mortem: GEMMs latency-bound at the per-step barrier drain
//   (K=1024 -> 32 steps x ~40-80cyc MFMA between ~800cyc drains). Fix:
//   stage 128x64 A + 64x64 B per step (24KB, 2 k-substeps, 16 MFMA/wave),
//   halving barrier count; LDS 48KB -> 3 blocks/CU; larger grids
//   (W1 2048 blocks, QKV 1536) for cross-block drain overlap.
// Workspace (80 MB):
//   [ 0, 6M) wqkv^T  [ 6, 8M) wo^T  [ 8,16M) w1^T  [16,24M) w2^T
//   [24,32M) h -> vt (V^T) -> h2    [32,56M) qkv -> g(32MB spans [32,64M))
//   [56,64M) ctx     [64,80M) x1 (fp32)

typedef __bf16 bf16x8_t __attribute__((ext_vector_type(8)));
typedef float f32x4_t __attribute__((ext_vector_type(4)));
typedef unsigned short u16x8 __attribute__((ext_vector_type(8)));

__device__ __forceinline__ unsigned short f2b(float f) {
    unsigned int u = __builtin_bit_cast(unsigned int, f);
    u += 0x7fffu + ((u >> 16) & 1u);   // round-to-nearest-even
    return (unsigned short)(u >> 16);
}
__device__ __forceinline__ bf16x8_t as_bf(u16x8 v) {
    return __builtin_bit_cast(bf16x8_t, v);
}
__device__ __forceinline__ void store_out(float* p, float v) { *p = v; }
__device__ __forceinline__ void store_out(unsigned short* p, float v) { *p = f2b(v); }

// async global->LDS, 16B per lane; lds dest must be wave-uniform base
__device__ __forceinline__ void glds16(const unsigned short* g, unsigned short* l) {
    __builtin_amdgcn_global_load_lds(
        (const __attribute__((address_space(1))) unsigned int*)g,
        (__attribute__((address_space(3))) unsigned int*)l, 16, 0, 0);
}

// -------------------------------------------------- transpose + cast weights
// src [K][N] fp32 -> dst [N][K] bf16
__global__ __launch_bounds__(256) void transpose_cast(
    const float* __restrict__ src, unsigned short* __restrict__ dst,
    int K, int N) {
    __shared__ float tile[32][33];
    const int k0 = blockIdx.x * 32, n0 = blockIdx.y * 32;
    const int c = threadIdx.x & 31, r8 = threadIdx.x >> 5;
#pragma unroll
    for (int i = 0; i < 4; i++) {
        const int r = r8 + i * 8;
        tile[r][c] = src[(size_t)(k0 + r) * N + n0 + c];
    }
    __syncthreads();
#pragma unroll
    for (int i = 0; i < 4; i++) {
        const int rr = r8 + i * 8;
        dst[(size_t)(n0 + rr) * K + k0 + c] = f2b(tile[c][rr]);
    }
}

// -------------------------------------------------- V -> V^T (per b, head-major)
__global__ __launch_bounds__(256) void vtrans_kernel(
    const unsigned short* __restrict__ src, unsigned short* __restrict__ dst) {
    __shared__ unsigned short tile[32][34];
    const int s0 = blockIdx.x * 32, hd0 = blockIdx.y * 32, b = blockIdx.z;
    const int c = threadIdx.x & 31, r8 = threadIdx.x >> 5;
#pragma unroll
    for (int i = 0; i < 4; i++) {
        const int r = r8 + i * 8;
        tile[r][c] = src[(size_t)(b * 2048 + s0 + r) * 3072 + hd0 + c];
    }
    __syncthreads();
#pragma unroll
    for (int i = 0; i < 4; i++) {
        const int rr = r8 + i * 8;
        dst[(size_t)(b * 1024 + hd0 + rr) * 2048 + s0 + c] = tile[c][rr];
    }
}

// ---------------------------------------------------------------- LayerNorm
__global__ __launch_bounds__(256) void ln_kernel(
    const float* __restrict__ X,
    const float* __restrict__ scale,
    const float* __restrict__ shift,
    unsigned short* __restrict__ Hout) {
    const int tok = blockIdx.x;
    const int tid = threadIdx.x;
    const size_t base = (size_t)tok * 1024 + tid * 4;
    float4 xv = *(const float4*)(X + base);
    float f[4] = {xv.x, xv.y, xv.z, xv.w};
    float s = 0.f, s2 = 0.f;
#pragma unroll
    for (int i = 0; i < 4; i++) { s += f[i]; s2 += f[i] * f[i]; }
#pragma unroll
    for (int off = 32; off >= 1; off >>= 1) {
        s += __shfl_down(s, off);
        s2 += __shfl_down(s2, off);
    }
    __shared__ float red[8];
    const int wv = tid >> 6;
    if ((tid & 63) == 0) { red[wv] = s; red[4 + wv] = s2; }
    __syncthreads();
    s = red[0] + red[1] + red[2] + red[3];
    s2 = red[4] + red[5] + red[6] + red[7];
    const float mean = s * (1.f / 1024.f);
    const float var = s2 * (1.f / 1024.f) - mean * mean;
    const float rstd = rsqrtf(var + 1e-5f);
    const float4 sc = *(const float4*)(scale + tid * 4);
    const float4 sh = *(const float4*)(shift + tid * 4);
    unsigned short ov[4];
    ov[0] = f2b((f[0] - mean) * rstd * sc.x + sh.x);
    ov[1] = f2b((f[1] - mean) * rstd * sc.y + sh.y);
    ov[2] = f2b((f[2] - mean) * rstd * sc.z + sh.z);
    ov[3] = f2b((f[3] - mean) * rstd * sc.w + sh.w);
    *(unsigned long long*)(Hout + base) = *(unsigned long long*)ov;
}

// ---------------------------------------------------------------- GEMM
// C[M,N] = A[M,K](bf16) @ Bt[N,K]^T(bf16) + bias (+res / gelu).
// BM=128, BN=64, BK=64. 4 waves, wave tile 64x32, 2 k-substeps per stage.
// LDS subtile (16 rows x 32 k): lane q*16+l holds row l, k q*8..+7 (1KB).
template <int EPI, typename OutT>
__global__ __launch_bounds__(256) void gemm_kernel(
    const unsigned short* __restrict__ A, const unsigned short* __restrict__ Bt,
    const float* __restrict__ bp0, const float* __restrict__ bp1,
    const float* __restrict__ bp2, const float* __restrict__ bp3,
    const float* __restrict__ res, OutT* __restrict__ C, int M, int N, int K) {
    __shared__ __align__(16) unsigned short As[2][16 * 512];  // (rb,kh) = rb*2+kh
    __shared__ __align__(16) unsigned short Bs[2][8 * 512];   // (nb,kh) = nb*2+kh
    const int tid = threadIdx.x;
    const int w = tid >> 6, lane = tid & 63;
    const int quad = lane >> 4, l16 = lane & 15;
    const int bm = blockIdx.x * 128, bn = blockIdx.y * 64;
    const int wm = (w & 1) * 64, wn = (w >> 1) * 32;

    f32x4_t acc[4][2];
#pragma unroll
    for (int i = 0; i < 4; i++)
#pragma unroll
        for (int j = 0; j < 2; j++) acc[i][j] = f32x4_t{0.f, 0.f, 0.f, 0.f};

    const unsigned short* Ab = A + (size_t)(bm + l16) * K + quad * 8;
    const unsigned short* Bb = Bt + (size_t)(bn + l16) * K + quad * 8;

    // stage one 128x64 A-tile + 64x64 B-tile (24 subtile issues, 6/wave)
    auto stage = [&](int kc, int bufi) {
        for (int s = w; s < 24; s += 4) {
            if (s < 16) {
                const int rb = s >> 1, kh = s & 1;
                glds16(Ab + (size_t)rb * 16 * K + kc + kh * 32, &As[bufi][s * 512]);
            } else {
                const int t2 = s - 16;
                const int nb = t2 >> 1, kh = t2 & 1;
                glds16(Bb + (size_t)nb * 16 * K + kc + kh * 32, &Bs[bufi][t2 * 512]);
            }
        }
    };

    stage(0, 0);
    __syncthreads();

    int buf = 0;
    for (int k0 = 0; k0 < K; k0 += 64) {
        if (k0 + 64 < K) stage(k0 + 64, buf ^ 1);
#pragma unroll
        for (int kh = 0; kh < 2; kh++) {
            bf16x8_t af[4], bfv[2];
#pragma unroll
            for (int i = 0; i < 4; i++)
                af[i] = as_bf(*(const u16x8*)&As[buf][((((wm >> 4) + i) << 1) + kh) * 512 + lane * 8]);
#pragma unroll
            for (int j = 0; j < 2; j++)
                bfv[j] = as_bf(*(const u16x8*)&Bs[buf][((((wn >> 4) + j) << 1) + kh) * 512 + lane * 8]);
#pragma unroll
            for (int i = 0; i < 4; i++)
#pragma unroll
                for (int j = 0; j < 2; j++)
                    acc[i][j] = __builtin_amdgcn_mfma_f32_16x16x32_bf16(af[i], bfv[j], acc[i][j], 0, 0, 0);
        }
        __syncthreads();
        buf ^= 1;
    }

    // epilogue: C/D layout col=l16, row=quad*4+r
#pragma unroll
    for (int i = 0; i < 4; i++) {
        const int row = bm + wm + i * 16 + quad * 4;
#pragma unroll
        for (int j = 0; j < 2; j++) {
            const int col = bn + wn + j * 16 + l16;
            const int sel = col >> 10;
            const float* bp = (sel == 0) ? bp0 : (sel == 1) ? bp1 : (sel == 2) ? bp2 : bp3;
            const float bv = bp[col & 1023];
#pragma unroll
            for (int r = 0; r < 4; r++) {
                float v = acc[i][j][r] + bv;
                if (EPI == 1) v += res[(size_t)(row + r) * N + col];
                if (EPI == 2) v = 0.5f * v * (1.f + erff(v * 0.70710678118f));
                store_out(&C[(size_t)(row + r) * N + col], v);
            }
        }
    }
}

// ---------------------------------------------------------------- Attention
// 128 Q-rows/block. Q,K: fused qkv rows (stride ld). Vt: [b*16+h][64][2048].
#define LP 68   // Ps stride (write banks quad*8+l16/2 -> conflict-free)

__global__ __launch_bounds__(256, 3) void attn_kernel(
    const unsigned short* __restrict__ Q, const unsigned short* __restrict__ K,
    const unsigned short* __restrict__ Vt, unsigned short* __restrict__ O,
    int ld) {
    __shared__ __align__(16) unsigned short Ks[2][8 * 512];
    __shared__ __align__(16) unsigned short Vs[2][8 * 512];
    __shared__ __align__(16) unsigned short Ps[4][32 * LP];
    const int tid = threadIdx.x;
    const int w = tid >> 6, lane = tid & 63;
    const int quad = lane >> 4, l16 = lane & 15;
    const int hh = blockIdx.x >> 1, bb = blockIdx.x & 1;
    const int y = blockIdx.y;
    const int qb = (y >= 8) ? (y - 8) : (15 - y);
    const int q0 = qb * 128;
    const int tmax = 2 * qb + 1;
    const size_t seqbase = (size_t)bb * 2048;
    const int hoff = hh * 64;
    const unsigned short* vtb = Vt + (size_t)(bb * 16 + hh) * 64 * 2048;
    const float cs = 0.18033688f;   // 0.125 * log2(e)

    bf16x8_t qf[2][2];
#pragma unroll
    for (int i = 0; i < 2; i++) {
        const unsigned short* qr = Q + (seqbase + q0 + i * 64 + w * 16 + l16) * ld + hoff;
        qf[i][0] = as_bf(*(const u16x8*)(qr + quad * 8));
        qf[i][1] = as_bf(*(const u16x8*)(qr + 32 + quad * 8));
    }

    f32x4_t o[2][4];
#pragma unroll
    for (int i = 0; i < 2; i++)
#pragma unroll
        for (int jd = 0; jd < 4; jd++) o[i][jd] = f32x4_t{0.f, 0.f, 0.f, 0.f};
    float ls[2][4] = {{0.f, 0.f, 0.f, 0.f}, {0.f, 0.f, 0.f, 0.f}};

    auto stage = [&](int t, int buf) {
        for (int s = w; s < 16; s += 4) {
            if (s < 8) {
                const unsigned short* src =
                    K + (seqbase + t * 64 + (s >> 1) * 16 + l16) * ld + hoff + (s & 1) * 32 + quad * 8;
                glds16(src, &Ks[buf][s * 512]);
            } else {
                const int v = s - 8;
                const unsigned short* src =
                    vtb + (size_t)((v >> 1) * 16 + l16) * 2048 + t * 64 + (v & 1) * 32 + quad * 8;
                glds16(src, &Vs[buf][v * 512]);
            }
        }
    };

    stage(0, 0);
    __syncthreads();

    int buf = 0;
    for (int t = 0; t <= tmax; ++t) {
        if (t < tmax) stage(t + 1, buf ^ 1);

        bf16x8_t kf[4][2], vf[4][2];
#pragma unroll
        for (int jn = 0; jn < 4; jn++) {
            kf[jn][0] = as_bf(*(const u16x8*)&Ks[buf][(jn * 2 + 0) * 512 + lane * 8]);
            kf[jn][1] = as_bf(*(const u16x8*)&Ks[buf][(jn * 2 + 1) * 512 + lane * 8]);
            vf[jn][0] = as_bf(*(const u16x8*)&Vs[buf][(jn * 2 + 0) * 512 + lane * 8]);
            vf[jn][1] = as_bf(*(const u16x8*)&Vs[buf][(jn * 2 + 1) * 512 + lane * 8]);
        }

#pragma unroll
        for (int i = 0; i < 2; i++) {
            if (i == 0 && t > 2 * qb) continue;
            const bool diag = (t == 2 * qb + i);
#pragma unroll
            for (int jn = 0; jn < 4; jn++) {
                f32x4_t z = f32x4_t{0.f, 0.f, 0.f, 0.f};
                z = __builtin_amdgcn_mfma_f32_16x16x32_bf16(qf[i][0], kf[jn][0], z, 0, 0, 0);
                z = __builtin_amdgcn_mfma_f32_16x16x32_bf16(qf[i][1], kf[jn][1], z, 0, 0, 0);
#pragma unroll
                for (int r = 0; r < 4; r++) {
                    float p = exp2f(fminf(z[r] * cs, 60.f));
                    if (diag) {
                        const int col = t * 64 + jn * 16 + l16;
                        const int row = q0 + i * 64 + w * 16 + quad * 4 + r;
                        p = (col <= row) ? p : 0.f;
                    }
                    ls[i][r] += p;
                    Ps[w][(i * 16 + quad * 4 + r) * LP + jn * 16 + l16] = f2b(p);
                }
            }
        }

#pragma unroll
        for (int i = 0; i < 2; i++) {
            if (i == 0 && t > 2 * qb) continue;
            const bf16x8_t pf0 = as_bf(*(const u16x8*)&Ps[w][(i * 16 + l16) * LP + quad * 8]);
            const bf16x8_t pf1 = as_bf(*(const u16x8*)&Ps[w][(i * 16 + l16) * LP + 32 + quad * 8]);
#pragma unroll
            for (int jd = 0; jd < 4; jd++) {
                o[i][jd] = __builtin_amdgcn_mfma_f32_16x16x32_bf16(pf0, vf[jd][0], o[i][jd], 0, 0, 0);
                o[i][jd] = __builtin_amdgcn_mfma_f32_16x16x32_bf16(pf1, vf[jd][1], o[i][jd], 0, 0, 0);
            }
        }
        __syncthreads();
        buf ^= 1;
    }

#pragma unroll
    for (int i = 0; i < 2; i++)
#pragma unroll
        for (int r = 0; r < 4; r++) {
            float s = ls[i][r];
            s += __shfl_xor(s, 1);
            s += __shfl_xor(s, 2);
            s += __shfl_xor(s, 4);
            s += __shfl_xor(s, 8);
            const float inv = 1.f / s;
            const size_t row = seqbase + q0 + i * 64 + w * 16 + quad * 4 + r;
#pragma unroll
            for (int jd = 0; jd < 4; jd++)
                O[row * 1024 + hoff + jd * 16 + l16] = f2b(o[i][jd][r] * inv);
        }
}

// ---------------------------------------------------------------- launch
extern "C" void kernel_launch(void* const* d_in, const int* in_sizes, int n_in,
                              void* d_out, int out_size, void* d_ws, size_t ws_size,
                              hipStream_t stream) {
    const float* x = (const float*)d_in[0];
    const float* ln1s = (const float*)d_in[1];
    const float* ln1b = (const float*)d_in[2];
    const float* ln2s = (const float*)d_in[3];
    const float* ln2b = (const float*)d_in[4];
    const float* wq = (const float*)d_in[5];
    const float* bq = (const float*)d_in[6];
    const float* wk = (const float*)d_in[7];
    const float* bk = (const float*)d_in[8];
    const float* wv = (const float*)d_in[9];
    const float* bv = (const float*)d_in[10];
    const float* wo = (const float*)d_in[11];
    const float* bo = (const float*)d_in[12];
    const float* w1 = (const float*)d_in[13];
    const float* b1 = (const float*)d_in[14];
    const float* w2 = (const float*)d_in[15];
    const float* b2 = (const float*)d_in[16];
    float* out = (float*)d_out;

    char* ws = (char*)d_ws;
    const size_t MB = 1u << 20;
    unsigned short* wqkvt = (unsigned short*)(ws + 0 * MB);
    unsigned short* wot   = (unsigned short*)(ws + 6 * MB);
    unsigned short* w1t   = (unsigned short*)(ws + 8 * MB);
    unsigned short* w2t   = (unsigned short*)(ws + 16 * MB);
    unsigned short* h     = (unsigned short*)(ws + 24 * MB);
    unsigned short* vt    = (unsigned short*)(ws + 24 * MB);
    unsigned short* qkv   = (unsigned short*)(ws + 32 * MB);
    unsigned short* ctx   = (unsigned short*)(ws + 56 * MB);
    unsigned short* h2    = (unsigned short*)(ws + 24 * MB);
    float*          x1    = (float*)(ws + 64 * MB);
    unsigned short* g     = (unsigned short*)(ws + 32 * MB);

    const dim3 blk(256);

    transpose_cast<<<dim3(32, 32), blk, 0, stream>>>(wq, wqkvt, 1024, 1024);
    transpose_cast<<<dim3(32, 32), blk, 0, stream>>>(wk, wqkvt + (1u << 20), 1024, 1024);
    transpose_cast<<<dim3(32, 32), blk, 0, stream>>>(wv, wqkvt + (2u << 20), 1024, 1024);
    transpose_cast<<<dim3(32, 32), blk, 0, stream>>>(wo, wot, 1024, 1024);
    transpose_cast<<<dim3(32, 128), blk, 0, stream>>>(w1, w1t, 1024, 4096);
    transpose_cast<<<dim3(128, 32), blk, 0, stream>>>(w2, w2t, 4096, 1024);

    ln_kernel<<<4096, blk, 0, stream>>>(x, ln1s, ln1b, h);
    // qkv = h @ [wq|wk|wv] + bias   (M=4096, N=3072, K=1024)
    gemm_kernel<0, unsigned short><<<dim3(32, 48), blk, 0, stream>>>(
        h, wqkvt, bq, bk, bv, bv, nullptr, qkv, 4096, 3072, 1024);
    vtrans_kernel<<<dim3(64, 32, 2), blk, 0, stream>>>(qkv + 2048, vt);
    attn_kernel<<<dim3(32, 16), blk, 0, stream>>>(qkv, qkv + 1024, vt, ctx, 3072);
    // x1 = ctx @ wo + bo + x
    gemm_kernel<1, float><<<dim3(32, 16), blk, 0, stream>>>(
        ctx, wot, bo, bo, bo, bo, x, x1, 4096, 1024, 1024);
    ln_kernel<<<4096, blk, 0, stream>>>(x1, ln2s, ln2b, h2);
    // g = gelu(h2 @ w1 + b1)   (M=4096, N=4096, K=1024)
    gemm_kernel<2, unsigned short><<<dim3(32, 64), blk, 0, stream>>>(
        h2, w1t, b1, b1 + 1024, b1 + 2048, b1 + 3072, nullptr, g, 4096, 4096, 1024);
    // out = g @ w2 + b2 + x1   (M=4096, N=1024, K=4096)
    gemm_kernel<1, float><<<dim3(32, 16), blk, 0, stream>>>(
        g, w2t, b2, b2, b2, b2, x1, out, 4096, 1024, 4096);
}